// Round 2
// baseline (4344.632 us; speedup 1.0000x reference)
//
#include <hip/hip_runtime.h>
#include <hip/hip_bf16.h>

// Problem constants
#define BB 4
#define NN 8192
#define SS 2048
#define KK 32
#define DD 64
#define CIN 67
#define PPIX (BB*SS*KK)      // 262144 pixels
#define CNT_F 262144.0f      // BN count = B*K*S
#define R2 0.04f
#define BN_EPS 1e-5f

typedef unsigned long long ull;

__global__ void zero_kernel(float* __restrict__ p, int n) {
    int i = blockIdx.x * 256 + threadIdx.x;
    if (i < n) p[i] = 0.0f;
}

// ---------------------------------------------------------------------------
// 1) Farthest point sampling: 1 block per batch, 1024 threads, 8 pts/thread.
//    Matches reference arithmetic: d = ((dx*dx + dy*dy) + dz*dz), no fma.
// ---------------------------------------------------------------------------
__global__ __launch_bounds__(1024) void fps_kernel(const float* __restrict__ xyz,
                                                   float* __restrict__ out_newxyz,
                                                   int* __restrict__ fps_idx) {
    const int b = blockIdx.x;
    const int t = threadIdx.x;
    const float* X = xyz + (size_t)b * NN * 3;

    float px[8], py[8], pz[8], dist[8];
#pragma unroll
    for (int j = 0; j < 8; j++) {
        int i = t + j * 1024;
        px[j] = X[3 * i];
        py[j] = X[3 * i + 1];
        pz[j] = X[3 * i + 2];
        dist[j] = 1e18f;
    }

    __shared__ int sFar;
    __shared__ ull sPart[16];
    if (t == 0) sFar = 0;
    __syncthreads();

    for (int s = 0; s < SS; s++) {
        int far = sFar;
        float cx = X[3 * far], cy = X[3 * far + 1], cz = X[3 * far + 2];
        if (t == 0) {
            fps_idx[b * SS + s] = far;
            out_newxyz[(size_t)(b * SS + s) * 3 + 0] = cx;
            out_newxyz[(size_t)(b * SS + s) * 3 + 1] = cy;
            out_newxyz[(size_t)(b * SS + s) * 3 + 2] = cz;
        }
        float bd = 0.0f;
        int bi = t;   // harmless default
#pragma unroll
        for (int j = 0; j < 8; j++) {
            float dx = __fsub_rn(px[j], cx);
            float dy = __fsub_rn(py[j], cy);
            float dz = __fsub_rn(pz[j], cz);
            float d = __fadd_rn(__fadd_rn(__fmul_rn(dx, dx), __fmul_rn(dy, dy)),
                                __fmul_rn(dz, dz));
            dist[j] = fminf(dist[j], d);
            if (dist[j] > bd) { bd = dist[j]; bi = t + j * 1024; }
        }
        // pack (dist, complemented index) so max => largest dist, ties -> smallest idx
        ull u = ((ull)__float_as_uint(bd) << 32) | (unsigned)(NN - 1 - bi);
#pragma unroll
        for (int off = 32; off; off >>= 1) {
            ull o = __shfl_xor(u, off, 64);
            if (o > u) u = o;
        }
        if ((t & 63) == 0) sPart[t >> 6] = u;
        __syncthreads();
        if (t == 0) {
            ull m = sPart[0];
#pragma unroll
            for (int wv = 1; wv < 16; wv++) if (sPart[wv] > m) m = sPart[wv];
            sFar = NN - 1 - (int)(m & 0xffffffffu);
        }
        __syncthreads();
    }
}

// ---------------------------------------------------------------------------
// 2) Query ball: one wave per query; scan chunks of 64 points in index order,
//    keep first 32 within radius. Expanded distance form matches reference.
// ---------------------------------------------------------------------------
__global__ __launch_bounds__(256) void ball_kernel(const float* __restrict__ xyz,
                                                   const float* __restrict__ newxyz,
                                                   int* __restrict__ idx_out) {
    const int wave = threadIdx.x >> 6;
    const int lane = threadIdx.x & 63;
    const int q = blockIdx.x * 4 + wave;
    const int b = q >> 11;            // q / 2048
    const float* X = xyz + (size_t)b * NN * 3;

    float sx = newxyz[(size_t)q * 3 + 0];
    float sy = newxyz[(size_t)q * 3 + 1];
    float sz = newxyz[(size_t)q * 3 + 2];
    float ssum = __fadd_rn(__fadd_rn(__fmul_rn(sx, sx), __fmul_rn(sy, sy)),
                           __fmul_rn(sz, sz));

    __shared__ int sIdx[4][32];
    int* my = sIdx[wave];

    int have = 0;
    for (int base = 0; base < NN && have < KK; base += 64) {
        int i = base + lane;
        float x = X[3 * i], y = X[3 * i + 1], z = X[3 * i + 2];
        float xsum = __fadd_rn(__fadd_rn(__fmul_rn(x, x), __fmul_rn(y, y)),
                               __fmul_rn(z, z));
        float dot = __fadd_rn(__fadd_rn(__fmul_rn(sx, x), __fmul_rn(sy, y)),
                              __fmul_rn(sz, z));
        float d = __fadd_rn(__fadd_rn(__fmul_rn(-2.0f, dot), ssum), xsum);
        d = fmaxf(d, 0.0f);
        bool in = (d <= R2);
        ull mask = __ballot(in);
        int pre = __popcll(mask & ((1ull << lane) - 1ull));
        if (in && (have + pre) < KK) my[have + pre] = i;
        have += __popcll(mask);
    }
    __syncthreads();
    if (lane < KK) {
        int v = (lane < have) ? my[lane] : my[0];
        idx_out[(size_t)q * KK + lane] = v;
    }
}

// ---------------------------------------------------------------------------
// 3) Layer 1: gather (gnorm ++ points) and 67->64 matmul. y layout [o][pixel].
// ---------------------------------------------------------------------------
#define ACC_C(NOUT4, cc, f)                                                        \
    {                                                                              \
        const float4* wr = (const float4*)(&wT[(cc) * (NOUT4) * 4]);               \
        _Pragma("unroll") for (int o4 = 0; o4 < (NOUT4); o4++) {                   \
            float4 wv = wr[o4];                                                    \
            acc[4 * o4 + 0] = fmaf(wv.x, (f), acc[4 * o4 + 0]);                    \
            acc[4 * o4 + 1] = fmaf(wv.y, (f), acc[4 * o4 + 1]);                    \
            acc[4 * o4 + 2] = fmaf(wv.z, (f), acc[4 * o4 + 2]);                    \
            acc[4 * o4 + 3] = fmaf(wv.w, (f), acc[4 * o4 + 3]);                    \
        }                                                                          \
    }

__global__ __launch_bounds__(256) void layer1_kernel(const float* __restrict__ xyz,
                                                     const float* __restrict__ points,
                                                     const float* __restrict__ newxyz,
                                                     const int* __restrict__ idx,
                                                     const float* __restrict__ w,
                                                     const float* __restrict__ bias,
                                                     float* __restrict__ y) {
    __shared__ __align__(16) float wT[CIN * 64];
    for (int i = threadIdx.x; i < CIN * 64; i += 256) {
        int o = i / CIN, c = i - o * CIN;
        wT[c * 64 + o] = w[i];
    }
    __syncthreads();

    const int p = blockIdx.x * 256 + threadIdx.x;
    const int b = p >> 16;           // / (S*K)
    const int sk = p & 65535;
    const int s = sk >> 5;
    const int pt = idx[p];

    const float* xr = xyz + ((size_t)b * NN + pt) * 3;
    const float* nr = newxyz + ((size_t)(b * SS + s)) * 3;
    float g0 = __fsub_rn(xr[0], nr[0]);
    float g1 = __fsub_rn(xr[1], nr[1]);
    float g2 = __fsub_rn(xr[2], nr[2]);

    float acc[64];
#pragma unroll
    for (int o = 0; o < 64; o++) acc[o] = bias[o];

    ACC_C(16, 0, g0);
    ACC_C(16, 1, g1);
    ACC_C(16, 2, g2);

    const float4* prow = (const float4*)(points + ((size_t)b * NN + pt) * DD);
#pragma unroll 4
    for (int c4 = 0; c4 < 16; c4++) {
        float4 f4 = prow[c4];
        ACC_C(16, 3 + 4 * c4 + 0, f4.x);
        ACC_C(16, 3 + 4 * c4 + 1, f4.y);
        ACC_C(16, 3 + 4 * c4 + 2, f4.z);
        ACC_C(16, 3 + 4 * c4 + 3, f4.w);
    }
#pragma unroll 8
    for (int o = 0; o < 64; o++) y[(size_t)o * PPIX + p] = acc[o];
}

// ---------------------------------------------------------------------------
// Mid/last layers: BN(coef)+ReLU on input, 64->COUT matmul.
// ---------------------------------------------------------------------------
template <int COUT>
__global__ __launch_bounds__(256) void layer_mid_kernel(const float* __restrict__ yin,
                                                        const float* __restrict__ coef,
                                                        const float* __restrict__ w,
                                                        const float* __restrict__ bias,
                                                        float* __restrict__ yout) {
    __shared__ __align__(16) float wT[64 * COUT];
    for (int i = threadIdx.x; i < 64 * COUT; i += 256) {
        int o = i >> 6, c = i & 63;
        wT[c * COUT + o] = w[i];
    }
    __syncthreads();

    const int p = blockIdx.x * 256 + threadIdx.x;
    float acc[COUT];
#pragma unroll
    for (int o = 0; o < COUT; o++) acc[o] = bias[o];

#pragma unroll 4
    for (int c = 0; c < 64; c++) {
        float f = fmaxf(fmaf(yin[(size_t)c * PPIX + p], coef[c], coef[64 + c]), 0.0f);
        ACC_C(COUT / 4, c, f);
    }
#pragma unroll 8
    for (int o = 0; o < COUT; o++) yout[(size_t)o * PPIX + p] = acc[o];
}

// ---------------------------------------------------------------------------
// Per-channel sum / sumsq. grid = C*32 blocks; each block does 8192 elements.
// ---------------------------------------------------------------------------
__global__ __launch_bounds__(256) void stats_kernel(const float* __restrict__ y,
                                                    float* __restrict__ sums) {
    const int c = blockIdx.x >> 5;
    const int chunk = blockIdx.x & 31;
    const float4* src = (const float4*)(y + (size_t)c * PPIX + (size_t)chunk * 8192);
    float s1 = 0.f, s2 = 0.f;
#pragma unroll
    for (int it = 0; it < 8; it++) {
        float4 v = src[(it << 8) + threadIdx.x];
        s1 += v.x + v.y + v.z + v.w;
        s2 = fmaf(v.x, v.x, s2);
        s2 = fmaf(v.y, v.y, s2);
        s2 = fmaf(v.z, v.z, s2);
        s2 = fmaf(v.w, v.w, s2);
    }
#pragma unroll
    for (int off = 32; off; off >>= 1) {
        s1 += __shfl_down(s1, off, 64);
        s2 += __shfl_down(s2, off, 64);
    }
    __shared__ float p1[4], p2[4];
    int wv = threadIdx.x >> 6;
    if ((threadIdx.x & 63) == 0) { p1[wv] = s1; p2[wv] = s2; }
    __syncthreads();
    if (threadIdx.x == 0) {
        atomicAdd(&sums[2 * c], p1[0] + p1[1] + p1[2] + p1[3]);
        atomicAdd(&sums[2 * c + 1], p2[0] + p2[1] + p2[2] + p2[3]);
    }
}

__global__ void coef_kernel(const float* __restrict__ sums,
                            const float* __restrict__ g,
                            const float* __restrict__ be,
                            float* __restrict__ coefOut, int C) {
    int c = threadIdx.x;
    if (c >= C) return;
    float mu = sums[2 * c] * (1.0f / CNT_F);
    float ex2 = sums[2 * c + 1] * (1.0f / CNT_F);
    float var = fmaxf(ex2 - mu * mu, 0.0f);
    float sc = g[c] / sqrtf(var + BN_EPS);
    coefOut[c] = sc;
    coefOut[C + c] = be[c] - mu * sc;
}

// ---------------------------------------------------------------------------
// Final: BN+ReLU then max over K=32, write new_points (B,128,S).
// ---------------------------------------------------------------------------
__global__ __launch_bounds__(256) void final_kernel(const float* __restrict__ y3,
                                                    const float* __restrict__ coef,
                                                    float* __restrict__ outp) {
    const int gid = blockIdx.x * 256 + threadIdx.x;   // ((b*128+o)*2048+s)
    const int s = gid & 2047;
    const int o = (gid >> 11) & 127;
    const int b = gid >> 18;
    const float sc = coef[o], sh = coef[128 + o];
    const float4* row = (const float4*)(y3 + (size_t)o * PPIX + ((size_t)(b * SS + s)) * KK);
    float m = 0.0f;
#pragma unroll
    for (int i = 0; i < 8; i++) {
        float4 v = row[i];
        m = fmaxf(m, fmaf(v.x, sc, sh));
        m = fmaxf(m, fmaf(v.y, sc, sh));
        m = fmaxf(m, fmaf(v.z, sc, sh));
        m = fmaxf(m, fmaf(v.w, sc, sh));
    }
    outp[gid] = m;   // m >= 0 already (relu folded into max with init 0)
}

// ---------------------------------------------------------------------------
// Workspace layout (peak 194 MB):
//   [0, 32KB)            fpsIdx
//   [32KB, 32KB+1MB)     ballIdx
//   [1.25MB, ...)        sums (768 f) + coef (768 f)
//   [2MB, 66MB)          y2  (64 MB)   -- layer2 output
//   [66MB, 194MB)        y3  (128 MB)  -- layer3 output; y1 (64 MB) aliased
//                        at 66MB (dead before layer3 writes y3)
// ---------------------------------------------------------------------------
extern "C" void kernel_launch(void* const* d_in, const int* in_sizes, int n_in,
                              void* d_out, int out_size, void* d_ws, size_t ws_size,
                              hipStream_t stream) {
    const float* xyz = (const float*)d_in[0];
    const float* points = (const float*)d_in[1];
    const float* w0 = (const float*)d_in[2];
    const float* b0 = (const float*)d_in[3];
    const float* g0 = (const float*)d_in[4];
    const float* be0 = (const float*)d_in[5];
    const float* w1 = (const float*)d_in[6];
    const float* b1 = (const float*)d_in[7];
    const float* g1 = (const float*)d_in[8];
    const float* be1 = (const float*)d_in[9];
    const float* w2 = (const float*)d_in[10];
    const float* b2 = (const float*)d_in[11];
    const float* g2 = (const float*)d_in[12];
    const float* be2 = (const float*)d_in[13];
    float* out = (float*)d_out;

    char* ws = (char*)d_ws;
    int* fpsIdx = (int*)ws;
    int* ballIdx = (int*)(ws + (32 << 10));
    float* sums = (float*)(ws + (1 << 20) + (256 << 10));
    float* coef = sums + 768;
    float* y2 = (float*)(ws + (2ull << 20));            // 64 MB
    float* y1 = (float*)(ws + (66ull << 20));           // 64 MB (aliased in y3)
    float* y3 = (float*)(ws + (66ull << 20));           // 128 MB

    zero_kernel<<<3, 256, 0, stream>>>(sums, 768);

    fps_kernel<<<BB, 1024, 0, stream>>>(xyz, out, fpsIdx);
    ball_kernel<<<(BB * SS) / 4, 256, 0, stream>>>(xyz, out, ballIdx);

    layer1_kernel<<<PPIX / 256, 256, 0, stream>>>(xyz, points, out, ballIdx, w0, b0, y1);
    stats_kernel<<<64 * 32, 256, 0, stream>>>(y1, sums + 0);
    coef_kernel<<<1, 64, 0, stream>>>(sums + 0, g0, be0, coef + 0, 64);

    layer_mid_kernel<64><<<PPIX / 256, 256, 0, stream>>>(y1, coef + 0, w1, b1, y2);
    stats_kernel<<<64 * 32, 256, 0, stream>>>(y2, sums + 256);
    coef_kernel<<<1, 64, 0, stream>>>(sums + 256, g1, be1, coef + 256, 64);

    layer_mid_kernel<128><<<PPIX / 256, 256, 0, stream>>>(y2, coef + 256, w2, b2, y3);
    stats_kernel<<<128 * 32, 256, 0, stream>>>(y3, sums + 512);
    coef_kernel<<<1, 128, 0, stream>>>(sums + 512, g2, be2, coef + 512, 128);

    final_kernel<<<(BB * 128 * SS) / 256, 256, 0, stream>>>(y3, coef + 512, out + BB * SS * 3);
}

// Round 3
// 2858.714 us; speedup vs baseline: 1.5198x; 1.5198x over previous
//
#include <hip/hip_runtime.h>
#include <hip/hip_bf16.h>

// Problem constants
#define BB 4
#define NN 8192
#define SS 2048
#define KK 32
#define DD 64
#define CIN 67
#define PPIX (BB*SS*KK)      // 262144 pixels
#define CNT_F 262144.0f      // BN count = B*K*S
#define R2 0.04f
#define BN_EPS 1e-5f

typedef unsigned long long ull;

__global__ void zero_kernel(float* __restrict__ p, int n) {
    int i = blockIdx.x * 256 + threadIdx.x;
    if (i < n) p[i] = 0.0f;
}

// ---------------------------------------------------------------------------
// 1) Farthest point sampling: 1 block/batch, 512 threads, 16 contiguous
//    points per thread held in registers. One barrier per iteration.
//    Exact reference arithmetic: d = ((dx*dx + dy*dy) + dz*dz), no fma.
//    Tie-break = first (smallest-index) max, matching jnp.argmax:
//      - within thread: strict > over ascending j
//      - within wave: ballot + ffs (lane order == index order, contiguous pts)
//      - across waves: packed u64 (distbits<<32 | (NN-1-idx)) max.
// ---------------------------------------------------------------------------
__global__ __launch_bounds__(512) void fps_kernel(const float* __restrict__ xyz,
                                                  float* __restrict__ out_newxyz) {
    const int b = blockIdx.x;
    const int t = threadIdx.x;
    const int w = t >> 6, lane = t & 63;
    const float* X = xyz + (size_t)b * NN * 3;

    float px[16], py[16], pz[16], dist[16];
#pragma unroll
    for (int j = 0; j < 16; j++) {
        int i = t * 16 + j;
        px[j] = X[3 * i];
        py[j] = X[3 * i + 1];
        pz[j] = X[3 * i + 2];
        dist[j] = 1e18f;
    }

    __shared__ ull sSlot[2][8];

    float cx = X[0], cy = X[1], cz = X[2];   // far = 0 initially

    for (int s = 0; s < SS; s++) {
        if (t == 0) {
            float* o = out_newxyz + (size_t)(b * SS + s) * 3;
            o[0] = cx; o[1] = cy; o[2] = cz;
        }
        float bd = 0.0f; int bj = 0;
#pragma unroll
        for (int j = 0; j < 16; j++) {
            float dx = __fsub_rn(px[j], cx);
            float dy = __fsub_rn(py[j], cy);
            float dz = __fsub_rn(pz[j], cz);
            float d = __fadd_rn(__fadd_rn(__fmul_rn(dx, dx), __fmul_rn(dy, dy)),
                                __fmul_rn(dz, dz));
            float nd = fminf(dist[j], d);
            dist[j] = nd;
            if (nd > bd) { bd = nd; bj = j; }   // strict >: keeps first max
        }
        float wm = bd;
#pragma unroll
        for (int off = 32; off; off >>= 1)
            wm = fmaxf(wm, __shfl_xor(wm, off, 64));
        ull eqmask = __ballot(bd == wm);
        if (lane == __ffsll(eqmask) - 1) {
            sSlot[s & 1][w] =
                ((ull)__float_as_uint(bd) << 32) | (unsigned)(NN - 1 - (t * 16 + bj));
        }
        __syncthreads();
        ull m = sSlot[s & 1][0];
#pragma unroll
        for (int i = 1; i < 8; i++) { ull v = sSlot[s & 1][i]; if (v > m) m = v; }
        int far = NN - 1 - (int)(m & 0xffffffffu);
        cx = X[3 * far]; cy = X[3 * far + 1]; cz = X[3 * far + 2];
    }
}

// ---------------------------------------------------------------------------
// 2) Query ball: one wave per query; scan chunks of 64 points in index order,
//    keep first 32 within radius. Expanded distance form matches reference.
// ---------------------------------------------------------------------------
__global__ __launch_bounds__(256) void ball_kernel(const float* __restrict__ xyz,
                                                   const float* __restrict__ newxyz,
                                                   int* __restrict__ idx_out) {
    const int wave = threadIdx.x >> 6;
    const int lane = threadIdx.x & 63;
    const int q = blockIdx.x * 4 + wave;
    const int b = q >> 11;            // q / 2048
    const float* X = xyz + (size_t)b * NN * 3;

    float sx = newxyz[(size_t)q * 3 + 0];
    float sy = newxyz[(size_t)q * 3 + 1];
    float sz = newxyz[(size_t)q * 3 + 2];
    float ssum = __fadd_rn(__fadd_rn(__fmul_rn(sx, sx), __fmul_rn(sy, sy)),
                           __fmul_rn(sz, sz));

    __shared__ int sIdx[4][32];
    int* my = sIdx[wave];

    int have = 0;
    for (int base = 0; base < NN && have < KK; base += 64) {
        int i = base + lane;
        float x = X[3 * i], y = X[3 * i + 1], z = X[3 * i + 2];
        float xsum = __fadd_rn(__fadd_rn(__fmul_rn(x, x), __fmul_rn(y, y)),
                               __fmul_rn(z, z));
        float dot = __fadd_rn(__fadd_rn(__fmul_rn(sx, x), __fmul_rn(sy, y)),
                              __fmul_rn(sz, z));
        float d = __fadd_rn(__fadd_rn(__fmul_rn(-2.0f, dot), ssum), xsum);
        d = fmaxf(d, 0.0f);
        bool in = (d <= R2);
        ull mask = __ballot(in);
        int pre = __popcll(mask & ((1ull << lane) - 1ull));
        if (in && (have + pre) < KK) my[have + pre] = i;
        have += __popcll(mask);
    }
    __syncthreads();
    if (lane < KK) {
        int v = (lane < have) ? my[lane] : my[0];
        idx_out[(size_t)q * KK + lane] = v;
    }
}

// ---------------------------------------------------------------------------
// 3) Layer 1: gather (gnorm ++ points) and 67->64 matmul. y layout [o][pixel].
// ---------------------------------------------------------------------------
#define ACC_C(NOUT4, cc, f)                                                        \
    {                                                                              \
        const float4* wr = (const float4*)(&wT[(cc) * (NOUT4) * 4]);               \
        _Pragma("unroll") for (int o4 = 0; o4 < (NOUT4); o4++) {                   \
            float4 wv = wr[o4];                                                    \
            acc[4 * o4 + 0] = fmaf(wv.x, (f), acc[4 * o4 + 0]);                    \
            acc[4 * o4 + 1] = fmaf(wv.y, (f), acc[4 * o4 + 1]);                    \
            acc[4 * o4 + 2] = fmaf(wv.z, (f), acc[4 * o4 + 2]);                    \
            acc[4 * o4 + 3] = fmaf(wv.w, (f), acc[4 * o4 + 3]);                    \
        }                                                                          \
    }

__global__ __launch_bounds__(256) void layer1_kernel(const float* __restrict__ xyz,
                                                     const float* __restrict__ points,
                                                     const float* __restrict__ newxyz,
                                                     const int* __restrict__ idx,
                                                     const float* __restrict__ w,
                                                     const float* __restrict__ bias,
                                                     float* __restrict__ y) {
    __shared__ __align__(16) float wT[CIN * 64];
    for (int i = threadIdx.x; i < CIN * 64; i += 256) {
        int o = i / CIN, c = i - o * CIN;
        wT[c * 64 + o] = w[i];
    }
    __syncthreads();

    const int p = blockIdx.x * 256 + threadIdx.x;
    const int b = p >> 16;           // / (S*K)
    const int sk = p & 65535;
    const int s = sk >> 5;
    const int pt = idx[p];

    const float* xr = xyz + ((size_t)b * NN + pt) * 3;
    const float* nr = newxyz + ((size_t)(b * SS + s)) * 3;
    float g0 = __fsub_rn(xr[0], nr[0]);
    float g1 = __fsub_rn(xr[1], nr[1]);
    float g2 = __fsub_rn(xr[2], nr[2]);

    float acc[64];
#pragma unroll
    for (int o = 0; o < 64; o++) acc[o] = bias[o];

    ACC_C(16, 0, g0);
    ACC_C(16, 1, g1);
    ACC_C(16, 2, g2);

    const float4* prow = (const float4*)(points + ((size_t)b * NN + pt) * DD);
#pragma unroll 4
    for (int c4 = 0; c4 < 16; c4++) {
        float4 f4 = prow[c4];
        ACC_C(16, 3 + 4 * c4 + 0, f4.x);
        ACC_C(16, 3 + 4 * c4 + 1, f4.y);
        ACC_C(16, 3 + 4 * c4 + 2, f4.z);
        ACC_C(16, 3 + 4 * c4 + 3, f4.w);
    }
#pragma unroll 8
    for (int o = 0; o < 64; o++) y[(size_t)o * PPIX + p] = acc[o];
}

// ---------------------------------------------------------------------------
// Mid layers: BN(scale/shift)+ReLU on 64-ch input, 64->64 matmul.
// Layer 3 (128 outputs) runs as TWO of these (output halves) - no acc spill.
// ---------------------------------------------------------------------------
__global__ __launch_bounds__(256) void layer_mid_kernel(const float* __restrict__ yin,
                                                        const float* __restrict__ cs,
                                                        const float* __restrict__ csh,
                                                        const float* __restrict__ w,
                                                        const float* __restrict__ bias,
                                                        float* __restrict__ yout) {
    __shared__ __align__(16) float wT[64 * 64];
    for (int i = threadIdx.x; i < 64 * 64; i += 256) {
        int o = i >> 6, c = i & 63;
        wT[c * 64 + o] = w[i];
    }
    __syncthreads();

    const int p = blockIdx.x * 256 + threadIdx.x;
    float acc[64];
#pragma unroll
    for (int o = 0; o < 64; o++) acc[o] = bias[o];

#pragma unroll 4
    for (int c = 0; c < 64; c++) {
        float f = fmaxf(fmaf(yin[(size_t)c * PPIX + p], cs[c], csh[c]), 0.0f);
        ACC_C(16, c, f);
    }
#pragma unroll 8
    for (int o = 0; o < 64; o++) yout[(size_t)o * PPIX + p] = acc[o];
}

// ---------------------------------------------------------------------------
// Per-channel sum / sumsq. grid = C*32 blocks; each block does 8192 elements.
// ---------------------------------------------------------------------------
__global__ __launch_bounds__(256) void stats_kernel(const float* __restrict__ y,
                                                    float* __restrict__ sums) {
    const int c = blockIdx.x >> 5;
    const int chunk = blockIdx.x & 31;
    const float4* src = (const float4*)(y + (size_t)c * PPIX + (size_t)chunk * 8192);
    float s1 = 0.f, s2 = 0.f;
#pragma unroll
    for (int it = 0; it < 8; it++) {
        float4 v = src[(it << 8) + threadIdx.x];
        s1 += v.x + v.y + v.z + v.w;
        s2 = fmaf(v.x, v.x, s2);
        s2 = fmaf(v.y, v.y, s2);
        s2 = fmaf(v.z, v.z, s2);
        s2 = fmaf(v.w, v.w, s2);
    }
#pragma unroll
    for (int off = 32; off; off >>= 1) {
        s1 += __shfl_down(s1, off, 64);
        s2 += __shfl_down(s2, off, 64);
    }
    __shared__ float p1[4], p2[4];
    int wv = threadIdx.x >> 6;
    if ((threadIdx.x & 63) == 0) { p1[wv] = s1; p2[wv] = s2; }
    __syncthreads();
    if (threadIdx.x == 0) {
        atomicAdd(&sums[2 * c], p1[0] + p1[1] + p1[2] + p1[3]);
        atomicAdd(&sums[2 * c + 1], p2[0] + p2[1] + p2[2] + p2[3]);
    }
}

__global__ void coef_kernel(const float* __restrict__ sums,
                            const float* __restrict__ g,
                            const float* __restrict__ be,
                            float* __restrict__ coefOut, int C) {
    int c = threadIdx.x;
    if (c >= C) return;
    float mu = sums[2 * c] * (1.0f / CNT_F);
    float ex2 = sums[2 * c + 1] * (1.0f / CNT_F);
    float var = fmaxf(ex2 - mu * mu, 0.0f);
    float sc = g[c] / sqrtf(var + BN_EPS);
    coefOut[c] = sc;
    coefOut[C + c] = be[c] - mu * sc;
}

// ---------------------------------------------------------------------------
// Final: BN+ReLU then max over K=32, write new_points (B,128,S).
// ---------------------------------------------------------------------------
__global__ __launch_bounds__(256) void final_kernel(const float* __restrict__ y3,
                                                    const float* __restrict__ coef,
                                                    float* __restrict__ outp) {
    const int gid = blockIdx.x * 256 + threadIdx.x;   // ((b*128+o)*2048+s)
    const int s = gid & 2047;
    const int o = (gid >> 11) & 127;
    const int b = gid >> 18;
    const float sc = coef[o], sh = coef[128 + o];
    const float4* row = (const float4*)(y3 + (size_t)o * PPIX + ((size_t)(b * SS + s)) * KK);
    float m = 0.0f;
#pragma unroll
    for (int i = 0; i < 8; i++) {
        float4 v = row[i];
        m = fmaxf(m, fmaf(v.x, sc, sh));
        m = fmaxf(m, fmaf(v.y, sc, sh));
        m = fmaxf(m, fmaf(v.z, sc, sh));
        m = fmaxf(m, fmaf(v.w, sc, sh));
    }
    outp[gid] = m;   // m >= 0 already (relu folded into max with init 0)
}

// ---------------------------------------------------------------------------
// Workspace layout (peak 194 MB):
//   [32KB, 32KB+1MB)     ballIdx
//   [1.25MB, ...)        sums (768 f) + coef (768 f)
//   [2MB, 66MB)          y2  (64 MB)   -- layer2 output
//   [66MB, 194MB)        y3  (128 MB)  -- layer3 output; y1 (64 MB) aliased
//                        at 66MB (dead before layer3 writes y3)
// ---------------------------------------------------------------------------
extern "C" void kernel_launch(void* const* d_in, const int* in_sizes, int n_in,
                              void* d_out, int out_size, void* d_ws, size_t ws_size,
                              hipStream_t stream) {
    const float* xyz = (const float*)d_in[0];
    const float* points = (const float*)d_in[1];
    const float* w0 = (const float*)d_in[2];
    const float* b0 = (const float*)d_in[3];
    const float* g0 = (const float*)d_in[4];
    const float* be0 = (const float*)d_in[5];
    const float* w1 = (const float*)d_in[6];
    const float* b1 = (const float*)d_in[7];
    const float* g1 = (const float*)d_in[8];
    const float* be1 = (const float*)d_in[9];
    const float* w2 = (const float*)d_in[10];
    const float* b2 = (const float*)d_in[11];
    const float* g2 = (const float*)d_in[12];
    const float* be2 = (const float*)d_in[13];
    float* out = (float*)d_out;

    char* ws = (char*)d_ws;
    int* ballIdx = (int*)(ws + (32 << 10));
    float* sums = (float*)(ws + (1 << 20) + (256 << 10));
    float* coef = sums + 768;
    float* y2 = (float*)(ws + (2ull << 20));            // 64 MB
    float* y1 = (float*)(ws + (66ull << 20));           // 64 MB (aliased in y3)
    float* y3 = (float*)(ws + (66ull << 20));           // 128 MB

    zero_kernel<<<3, 256, 0, stream>>>(sums, 768);

    fps_kernel<<<BB, 512, 0, stream>>>(xyz, out);
    ball_kernel<<<(BB * SS) / 4, 256, 0, stream>>>(xyz, out, ballIdx);

    layer1_kernel<<<PPIX / 256, 256, 0, stream>>>(xyz, points, out, ballIdx, w0, b0, y1);
    stats_kernel<<<64 * 32, 256, 0, stream>>>(y1, sums + 0);
    coef_kernel<<<1, 64, 0, stream>>>(sums + 0, g0, be0, coef + 0, 64);

    layer_mid_kernel<<<PPIX / 256, 256, 0, stream>>>(y1, coef + 0, coef + 64, w1, b1, y2);
    stats_kernel<<<64 * 32, 256, 0, stream>>>(y2, sums + 256);
    coef_kernel<<<1, 64, 0, stream>>>(sums + 256, g1, be1, coef + 256, 64);

    // layer 3 = two 64-output halves (avoids acc[128] register spill)
    layer_mid_kernel<<<PPIX / 256, 256, 0, stream>>>(y2, coef + 256, coef + 320,
                                                     w2, b2, y3);
    layer_mid_kernel<<<PPIX / 256, 256, 0, stream>>>(y2, coef + 256, coef + 320,
                                                     w2 + 64 * 64, b2 + 64,
                                                     y3 + (size_t)64 * PPIX);
    stats_kernel<<<128 * 32, 256, 0, stream>>>(y3, sums + 512);
    coef_kernel<<<1, 128, 0, stream>>>(sums + 512, g2, be2, coef + 512, 128);

    final_kernel<<<(BB * 128 * SS) / 256, 256, 0, stream>>>(y3, coef + 512, out + BB * SS * 3);
}